// Round 3
// baseline (346.780 us; speedup 1.0000x reference)
//
#include <hip/hip_runtime.h>

typedef __bf16 bf16x8 __attribute__((ext_vector_type(8)));
typedef float floatx4 __attribute__((ext_vector_type(4)));
typedef unsigned short ushort8 __attribute__((ext_vector_type(8)));

__device__ __forceinline__ unsigned short f2bf(float f) {
    unsigned u = __float_as_uint(f);
    u += 0x7fffu + ((u >> 16) & 1u);   // round-to-nearest-even
    return (unsigned short)(u >> 16);
}

// ---------------------------------------------------------------------------
// Circuit helpers. State split 8-way: lane = p*8 + s8 (s8 = sample-in-wave).
// Thread p holds global amplitudes i = p*8 + j (j in [0,8)).
// Qubit q <-> amp bit (32>>q): q0=bit32(p&4), q1=bit16(p&2), q2=bit8(p&1)
// cross-thread (shfl_xor 32/16/8); q3=bit4(j&4), q4=bit2(j&2), q5=bit1(j&1)
// thread-local. Per-amplitude arithmetic identical to the proven kernel.
// ---------------------------------------------------------------------------
template <int ST>   // ST in {4,2,1}: thread-local gate
__device__ __forceinline__ void apply_local(float* fr, float* fi,
    float m00r, float m00i, float m01r, float m01i,
    float m10r, float m10i, float m11r, float m11i) {
#pragma unroll
    for (int i = 0; i < 8; ++i) {
        if ((i & ST) == 0) {
            int i1 = i + ST;
            float r0 = fr[i], u0 = fi[i], r1 = fr[i1], u1 = fi[i1];
            fr[i]  = m00r * r0 - m00i * u0 + m01r * r1 - m01i * u1;
            fi[i]  = m00r * u0 + m00i * r0 + m01r * u1 + m01i * r1;
            fr[i1] = m10r * r0 - m10i * u0 + m11r * r1 - m11i * u1;
            fi[i1] = m10r * u0 + m10i * r0 + m11r * u1 + m11i * r1;
        }
    }
}

template <int XM>   // XM in {32,16,8}: cross-thread gate; hi = bit=1 side
__device__ __forceinline__ void apply_cross(float* fr, float* fi, bool hi,
    float m00r, float m00i, float m01r, float m01i,
    float m10r, float m10i, float m11r, float m11i) {
    float car = hi ? m10r : m00r, cai = hi ? m10i : m00i;
    float cbr = hi ? m11r : m01r, cbi = hi ? m11i : m01i;
#pragma unroll
    for (int j = 0; j < 8; ++j) {
        float mr = fr[j], mi = fi[j];
        float pr = __shfl_xor(mr, XM);
        float pi = __shfl_xor(mi, XM);
        float a0r = hi ? pr : mr, a0i = hi ? pi : mi;
        float a1r = hi ? mr : pr, a1i = hi ? mi : pi;
        fr[j] = car * a0r - cai * a0i + cbr * a1r - cbi * a1i;
        fi[j] = car * a0i + cai * a0r + cbr * a1i + cbi * a1r;
    }
}

#define SWAP2(a, b) { float _t = fr[a]; fr[a] = fr[b]; fr[b] = _t; \
                      _t = fi[a]; fi[a] = fi[b]; fi[b] = _t; }

// ---------------------------------------------------------------------------
// Fused front: 553 blocks x 512 threads.
// Blocks 512..552: w2t transpose prep. Blocks 0..511: enc (8-way split-K,
// 32-iteration chains) + circuit (8 thr/sample, all 8 waves active) + z->g.
// LDS: part[8][64][33] = 66 KB; hsh/casa/zsh alias dead part regions after
// their producing barriers -> 68.2 KB total = 2 blocks/CU = 4 waves/SIMD
// through every phase (R2 had 2 waves/SIMD).
// ---------------------------------------------------------------------------
__global__ __launch_bounds__(512, 4) void fused_front(
    const float* __restrict__ x, const float* __restrict__ w1,
    const float* __restrict__ b1, const float* __restrict__ w2,
    const float* __restrict__ b2, const float* __restrict__ qw,
    const float* __restrict__ hw1, const float* __restrict__ hb1,
    const float* __restrict__ hw2,
    unsigned short* __restrict__ w2t, unsigned short* __restrict__ g) {

    if (blockIdx.x >= 512) {
        // ---- prep: transpose head_w2 [128][1296] fp32 -> w2t [1296][128] bf16
        int t = (blockIdx.x - 512) * 512 + threadIdx.x;   // 41*512 = 20992 >= 20736
        int nn = t >> 4;
        int kc = (t & 15) * 8;
        if (nn < 1296) {
            ushort8 pk;
#pragma unroll
            for (int j = 0; j < 8; ++j) pk[j] = f2bf(hw2[(size_t)(kc + j) * 1296 + nn]);
            *(ushort8*)(w2t + (size_t)nn * 128 + kc) = pk;
        }
        return;   // prep blocks execute no barriers
    }

    __shared__ float part[8][64][33];  // 67584 B; +1 pad: conflict-free
    __shared__ float umat_s[144];      // 18 Rot matrices * 8 floats

    // Aliases into dead part regions (each safe: producer phase only writes
    // slots the same thread just consumed, or a barrier separates phases).
    float (*hsh)[33] = part[0];                   // valid after reduce phase
    float (*casa)[12] = (float (*)[12])part[1];   // valid after angle phase
    float (*zsh)[6]   = (float (*)[6])part[2];    // valid after circuit

    int tid = threadIdx.x;

    // ---- phase 0: Rot matrices (covered by the enc barrier) ----------------
    if (tid < 18) {
        float phi = qw[tid * 3], theta = qw[tid * 3 + 1], omega = qw[tid * 3 + 2];
        float c = cosf(0.5f * theta), s = sinf(0.5f * theta);
        float po = 0.5f * (phi + omega), pm = 0.5f * (phi - omega);
        float epr = cosf(po), epi = -sinf(po);
        float emr = cosf(pm), emi = -sinf(pm);
        float* u = umat_s + tid * 8;
        u[0] = epr * c;  u[1] = epi * c;     // u00
        u[2] = -emr * s; u[3] = emi * s;     // u01 = -conj(em)*s
        u[4] = emr * s;  u[5] = emi * s;     // u10
        u[6] = epr * c;  u[7] = -epi * c;    // u11 = conj(ep)*c
    }

    // ---- phase 1: enc, 8-way split-K (32-iter chains, was 64) --------------
    int lane = tid & 63;
    int wave = tid >> 6;                    // 0..7
    int swave = __builtin_amdgcn_readfirstlane(wave);
    size_t row = (size_t)blockIdx.x * 64 + lane;
    const float2* x2 = (const float2*)(x + row * 512 + swave * 64);
    const float* wseg = w1 + swave * 64 * 32;  // wave-uniform -> scalar loads

    float acc[32];
#pragma unroll
    for (int j = 0; j < 32; ++j) acc[j] = 0.f;

#pragma clang loop unroll(disable)
    for (int k2 = 0; k2 < 32; ++k2) {
        float2 xv = x2[k2];
        const float* wr = wseg + k2 * 64;
#pragma unroll
        for (int j = 0; j < 32; ++j) acc[j] = fmaf(wr[j], xv.x, acc[j]);
#pragma unroll
        for (int j = 0; j < 32; ++j) acc[j] = fmaf(wr[32 + j], xv.y, acc[j]);
    }
#pragma unroll
    for (int j = 0; j < 32; ++j) part[wave][lane][j] = acc[j];
    __syncthreads();

    // reduce 8 partials + bias + tanh -> hsh (aliases part[0]; each thread
    // writes only the (rl,j) slots it alone reads)
    {
        int rl = tid & 63;
        int jg = (tid >> 6) * 4;
#pragma unroll
        for (int jj = 0; jj < 4; ++jj) {
            int j = jg + jj;
            float v = b1[j];
#pragma unroll
            for (int w = 0; w < 8; ++w) v += part[w][rl][j];
            hsh[rl][j] = tanhf(v);
        }
    }
    __syncthreads();

    // ---- phase 2: angles -> cos/sin (384 threads: 64 rows x 6 q) -----------
    if (tid < 384) {
        int row_a = tid & 63;
        int q = tid >> 6;   // 0..5
        float a = b2[q];
#pragma unroll
        for (int j = 0; j < 32; ++j) a = fmaf(hsh[row_a][j], w2[j * 6 + q], a);
        a *= 0.5f;
        casa[row_a][q * 2]     = cosf(a);
        casa[row_a][q * 2 + 1] = sinf(a);
    }
    __syncthreads();

    // ---- phase 3: circuit, 8 threads per sample ----------------------------
    int s8 = lane & 7;
    int p = lane >> 3;                  // 0..7
    int samp = wave * 8 + s8;           // 0..63
    bool pb4 = (p & 4) != 0, pb2 = (p & 2) != 0, pb1 = (p & 1) != 0;

    float ca[6], sa[6];
#pragma unroll
    for (int q = 0; q < 6; ++q) { ca[q] = casa[samp][q * 2]; sa[q] = casa[samp][q * 2 + 1]; }

    float fr[8], fi[8];
#pragma unroll
    for (int j = 0; j < 8; ++j) { fr[j] = 0.f; fi[j] = 0.f; }
    fr[0] = (p == 0) ? 1.f : 0.f;

#pragma clang loop unroll(disable)
    for (int layer = 0; layer < 3; ++layer) {
        const float* ub = umat_s + layer * 48;
#define MAT(Q)                                                            \
        const float* u = ub + (Q) * 8;                                    \
        float c = ca[Q], ss = sa[Q];                                      \
        float m00r = u[0] * c + u[2] * ss, m00i = u[1] * c + u[3] * ss;   \
        float m01r = u[2] * c - u[0] * ss, m01i = u[3] * c - u[1] * ss;   \
        float m10r = u[4] * c + u[6] * ss, m10i = u[5] * c + u[7] * ss;   \
        float m11r = u[6] * c - u[4] * ss, m11i = u[7] * c - u[5] * ss;
        { MAT(0) apply_cross<32>(fr, fi, pb4, m00r, m00i, m01r, m01i, m10r, m10i, m11r, m11i); }
        { MAT(1) apply_cross<16>(fr, fi, pb2, m00r, m00i, m01r, m01i, m10r, m10i, m11r, m11i); }
        { MAT(2) apply_cross<8>(fr, fi, pb1, m00r, m00i, m01r, m01i, m10r, m10i, m11r, m11i); }
        { MAT(3) apply_local<4>(fr, fi, m00r, m00i, m01r, m01i, m10r, m10i, m11r, m11i); }
        { MAT(4) apply_local<2>(fr, fi, m00r, m00i, m01r, m01i, m10r, m10i, m11r, m11i); }
        { MAT(5) apply_local<1>(fr, fi, m00r, m00i, m01r, m01i, m10r, m10i, m11r, m11i); }
#undef MAT
        // CNOT(0,1): control bit32 (p&4) -> flip bit16: exchange lane^16
#pragma unroll
        for (int j = 0; j < 8; ++j) {
            float pr = __shfl_xor(fr[j], 16);
            float pi = __shfl_xor(fi[j], 16);
            fr[j] = pb4 ? pr : fr[j];
            fi[j] = pb4 ? pi : fi[j];
        }
        // CNOT(2,3): control bit8 (p&1) -> flip bit4 (local j^4)
        {
            float tr[8], ti[8];
#pragma unroll
            for (int j = 0; j < 8; ++j) { tr[j] = fr[j]; ti[j] = fi[j]; }
#pragma unroll
            for (int j = 0; j < 8; ++j) {
                fr[j] = pb1 ? tr[j ^ 4] : tr[j];
                fi[j] = pb1 ? ti[j ^ 4] : ti[j];
            }
        }
        // CNOT(4,5): control bit2 (j&2) -> flip bit1
        SWAP2(2, 3) SWAP2(6, 7)
        // CNOT(1,2): control bit16 (p&2) -> flip bit8: exchange lane^8
#pragma unroll
        for (int j = 0; j < 8; ++j) {
            float pr = __shfl_xor(fr[j], 8);
            float pi = __shfl_xor(fi[j], 8);
            fr[j] = pb2 ? pr : fr[j];
            fi[j] = pb2 ? pi : fi[j];
        }
        // CNOT(3,4): control bit4 (j&4) -> flip bit2
        SWAP2(4, 6) SWAP2(5, 7)
        // CNOT(5,0): control bit1 (j odd) -> flip bit32: exchange lane^32
#pragma unroll
        for (int j = 1; j < 8; j += 2) {
            fr[j] = __shfl_xor(fr[j], 32);
            fi[j] = __shfl_xor(fi[j], 32);
        }
    }

    // ---- z expectations: per-thread partials, butterfly over 8 parts -------
    float zt = 0.f, z3 = 0.f, z4 = 0.f, z5 = 0.f;
#pragma unroll
    for (int j = 0; j < 8; ++j) {
        float pp = fr[j] * fr[j] + fi[j] * fi[j];
        zt += pp;
        z3 += (j & 4) ? -pp : pp;
        z4 += (j & 2) ? -pp : pp;
        z5 += (j & 1) ? -pp : pp;
    }
    float zz[6];
    zz[0] = pb4 ? -zt : zt;
    zz[1] = pb2 ? -zt : zt;
    zz[2] = pb1 ? -zt : zt;
    zz[3] = z3; zz[4] = z4; zz[5] = z5;
#pragma unroll
    for (int q = 0; q < 6; ++q) {
        zz[q] += __shfl_xor(zz[q], 8);
        zz[q] += __shfl_xor(zz[q], 16);
        zz[q] += __shfl_xor(zz[q], 32);
    }
    if (p < 6) zsh[samp][p] = zz[p];
    __syncthreads();

    // ---- head layer 1 -> g (bf16): 512 thr x 16 outs, fully coalesced ------
    int samp_h = wave * 8 + (lane >> 3);
    int seg = lane & 7;
    float z6[6];
#pragma unroll
    for (int q = 0; q < 6; ++q) z6[q] = zsh[samp_h][q];
    size_t sglob = (size_t)blockIdx.x * 64 + samp_h;
    unsigned short* gp = g + sglob * 128 + seg * 16;
#pragma unroll
    for (int j0 = 0; j0 < 16; j0 += 8) {
        ushort8 pk;
#pragma unroll
        for (int jj = 0; jj < 8; ++jj) {
            int j = seg * 16 + j0 + jj;
            float a = hb1[j];
#pragma unroll
            for (int q = 0; q < 6; ++q) a = fmaf(z6[q], hw1[q * 128 + j], a);
            a = fmaxf(a, 0.f);
            pk[jj] = f2bf(a);
        }
        *(ushort8*)(gp + j0) = pk;
    }
}

// ---------------------------------------------------------------------------
// K3: head GEMM — out[32768][1296] = g@w2t^T + b2.
// v2: one block owns 32 rows x ALL 1296 cols (block write range = exactly
// 1296 full 128-B lines, line-aligned) so every partial-line seam is merged
// inside ONE XCD's L2 -> no cross-XCD false sharing, no partial-line RMW at
// HBM. nt dropped so L2 actually merges. g tile hoisted to registers
// (reused across all 27 n-tiles). 1024 blocks = 4/CU = 16 waves/CU.
// ---------------------------------------------------------------------------
__global__ __launch_bounds__(256) void head_gemm(
    const unsigned short* __restrict__ g, const unsigned short* __restrict__ w2t,
    const float* __restrict__ b2, float* __restrict__ out) {
    int lane = threadIdx.x & 63;
    int wv = threadIdx.x >> 6;          // 0..3
    int row0 = blockIdx.x * 32;         // 1024 blocks * 32 rows
    int l15 = lane & 15, quad = lane >> 4;

    // hoist g tile: 32 rows x 128 k, reused by all 27 n-tiles
    const unsigned short* bp = g + (size_t)(row0 + l15) * 128 + quad * 8;
    bf16x8 bfr[2][4];
#pragma unroll
    for (int sub = 0; sub < 2; ++sub)
#pragma unroll
        for (int ks = 0; ks < 4; ++ks)
            bfr[sub][ks] = *(const bf16x8*)(bp + (size_t)sub * 16 * 128 + ks * 32);

    for (int n = wv; n < 27; n += 4) {
        int col0 = n * 48;
        const unsigned short* ap = w2t + (size_t)(col0 + l15) * 128 + quad * 8;

        floatx4 acc[6];  // [t][sub]
#pragma unroll
        for (int i = 0; i < 6; ++i) acc[i] = (floatx4)0.f;

#pragma unroll
        for (int ks = 0; ks < 4; ++ks) {
            bf16x8 af[3];
#pragma unroll
            for (int t = 0; t < 3; ++t) af[t] = *(const bf16x8*)(ap + (size_t)t * 16 * 128 + ks * 32);
#pragma unroll
            for (int t = 0; t < 3; ++t)
#pragma unroll
                for (int sub = 0; sub < 2; ++sub)
                    acc[t * 2 + sub] = __builtin_amdgcn_mfma_f32_16x16x32_bf16(af[t], bfr[sub][ks], acc[t * 2 + sub], 0, 0, 0);
        }

#pragma unroll
        for (int t = 0; t < 3; ++t) {
            const float* bb = b2 + col0 + t * 16 + quad * 4;
            floatx4 bias = { bb[0], bb[1], bb[2], bb[3] };
#pragma unroll
            for (int sub = 0; sub < 2; ++sub) {
                floatx4 v = acc[t * 2 + sub] + bias;
                floatx4* dst = (floatx4*)(out + (size_t)(row0 + sub * 16 + l15) * 1296 + col0 + t * 16 + quad * 4);
                *dst = v;   // regular store: L2 merges 64-B halves into full lines
            }
        }
    }
}

// ---------------------------------------------------------------------------
extern "C" void kernel_launch(void* const* d_in, const int* in_sizes, int n_in,
                              void* d_out, int out_size, void* d_ws, size_t ws_size,
                              hipStream_t stream) {
    const float* x   = (const float*)d_in[0];
    const float* ew1 = (const float*)d_in[1];
    const float* eb1 = (const float*)d_in[2];
    const float* ew2 = (const float*)d_in[3];
    const float* eb2 = (const float*)d_in[4];
    const float* qw  = (const float*)d_in[5];
    const float* hw1 = (const float*)d_in[6];
    const float* hb1 = (const float*)d_in[7];
    const float* hw2 = (const float*)d_in[8];
    const float* hb2 = (const float*)d_in[9];
    float* out = (float*)d_out;

    char* ws = (char*)d_ws;
    unsigned short* g   = (unsigned short*)(ws);             // 32768*128*2 = 8388608 B
    unsigned short* w2t = (unsigned short*)(ws + 8388608);   // 1296*128*2  = 331776 B

    fused_front<<<dim3(553), dim3(512), 0, stream>>>(x, ew1, eb1, ew2, eb2, qw, hw1, hb1, hw2, w2t, g);
    head_gemm<<<dim3(1024), dim3(256), 0, stream>>>(g, w2t, hb2, out);
}

// Round 5
// 340.991 us; speedup vs baseline: 1.0170x; 1.0170x over previous
//
#include <hip/hip_runtime.h>

typedef __bf16 bf16x8 __attribute__((ext_vector_type(8)));
typedef float floatx4 __attribute__((ext_vector_type(4)));
typedef unsigned short ushort8 __attribute__((ext_vector_type(8)));

__device__ __forceinline__ unsigned short f2bf(float f) {
    unsigned u = __float_as_uint(f);
    u += 0x7fffu + ((u >> 16) & 1u);   // round-to-nearest-even
    return (unsigned short)(u >> 16);
}

// ---------------------------------------------------------------------------
// Circuit helpers. State split 8-way: lane = p*8 + s8 (s8 = sample-in-wave).
// Thread p holds global amplitudes i = p*8 + j (j in [0,8)).
// Qubit q <-> amp bit (32>>q): q0=bit32(p&4), q1=bit16(p&2), q2=bit8(p&1)
// cross-thread (shfl_xor 32/16/8); q3..q5 thread-local. Per-amplitude
// arithmetic identical to the proven kernel.
// ---------------------------------------------------------------------------
template <int ST>   // ST in {4,2,1}: thread-local gate
__device__ __forceinline__ void apply_local(float* fr, float* fi,
    float m00r, float m00i, float m01r, float m01i,
    float m10r, float m10i, float m11r, float m11i) {
#pragma unroll
    for (int i = 0; i < 8; ++i) {
        if ((i & ST) == 0) {
            int i1 = i + ST;
            float r0 = fr[i], u0 = fi[i], r1 = fr[i1], u1 = fi[i1];
            fr[i]  = m00r * r0 - m00i * u0 + m01r * r1 - m01i * u1;
            fi[i]  = m00r * u0 + m00i * r0 + m01r * u1 + m01i * r1;
            fr[i1] = m10r * r0 - m10i * u0 + m11r * r1 - m11i * u1;
            fi[i1] = m10r * u0 + m10i * r0 + m11r * u1 + m11i * r1;
        }
    }
}

template <int XM>   // XM in {32,16,8}: cross-thread gate; hi = bit=1 side
__device__ __forceinline__ void apply_cross(float* fr, float* fi, bool hi,
    float m00r, float m00i, float m01r, float m01i,
    float m10r, float m10i, float m11r, float m11i) {
    float car = hi ? m10r : m00r, cai = hi ? m10i : m00i;
    float cbr = hi ? m11r : m01r, cbi = hi ? m11i : m01i;
#pragma unroll
    for (int j = 0; j < 8; ++j) {
        float mr = fr[j], mi = fi[j];
        float pr = __shfl_xor(mr, XM);
        float pi = __shfl_xor(mi, XM);
        float a0r = hi ? pr : mr, a0i = hi ? pi : mi;
        float a1r = hi ? mr : pr, a1i = hi ? mi : pi;
        fr[j] = car * a0r - cai * a0i + cbr * a1r - cbi * a1i;
        fi[j] = car * a0i + cai * a0r + cbr * a1i + cbi * a1r;
    }
}

#define SWAP2(a, b) { float _t = fr[a]; fr[a] = fr[b]; fr[b] = _t; \
                      _t = fi[a]; fi[a] = fi[b]; fi[b] = _t; }

// ---------------------------------------------------------------------------
// K0: prep — transpose head_w2 [128][1296] fp32 -> w2t [1296][128] bf16.
// Separate (stream-ordered) launch: mega's GEMM phase needs ALL of w2t and
// cross-block completion inside one launch is not guaranteed (G16).
// ---------------------------------------------------------------------------
__global__ __launch_bounds__(512) void prep_kernel(
    const float* __restrict__ hw2, unsigned short* __restrict__ w2t) {
    int t = blockIdx.x * 512 + threadIdx.x;   // 41*512 = 20992 >= 20736
    int nn = t >> 4;
    int kc = (t & 15) * 8;
    if (nn < 1296) {
        ushort8 pk;
#pragma unroll
        for (int j = 0; j < 8; ++j) pk[j] = f2bf(hw2[(size_t)(kc + j) * 1296 + nn]);
        *(ushort8*)(w2t + (size_t)nn * 128 + kc) = pk;
    }
}

// ---------------------------------------------------------------------------
// K1: mega — one block (512 thr) owns 64 samples END TO END:
//   enc (8-way split-K) -> circuit (8 thr/sample) -> g in LDS (16 KB,
//   XOR-swizzled, aliases dead enc scratch) -> head GEMM for rows
//   [64b, 64b+64) x all 1296 cols.
// g never touches global memory; one launch boundary and 16 MB of traffic
// removed vs R3. 512 blocks = 2/CU (LDS 68 KB) = 16 waves/CU everywhere.
// All arithmetic bit-identical to the R3 passing kernel.
// ---------------------------------------------------------------------------
__global__ __launch_bounds__(512, 4) void mega_kernel(
    const float* __restrict__ x, const float* __restrict__ w1,
    const float* __restrict__ b1, const float* __restrict__ w2,
    const float* __restrict__ b2, const float* __restrict__ qw,
    const float* __restrict__ hw1, const float* __restrict__ hb1,
    const unsigned short* __restrict__ w2t, const float* __restrict__ hb2,
    float* __restrict__ out) {

    __shared__ float part[8][64][33];  // 67584 B; +1 pad: conflict-free
    __shared__ float umat_s[144];      // 18 Rot matrices * 8 floats

    // Aliases into dead part regions (each producer/consumer pair separated
    // by a barrier, or same-thread-slot reuse):
    float (*hsh)[33] = part[0];                   // valid after reduce
    float (*casa)[12] = (float (*)[12])part[1];   // valid after angle phase
    char* gl = (char*)&part[3][0][0];             // g tile: 64*256 B = 16 KB
                                                  // (fits part[3..4] = 16896 B)
    int tid = threadIdx.x;

    // ---- phase 0: Rot matrices (covered by the enc barrier) ----------------
    if (tid < 18) {
        float phi = qw[tid * 3], theta = qw[tid * 3 + 1], omega = qw[tid * 3 + 2];
        float c = cosf(0.5f * theta), s = sinf(0.5f * theta);
        float po = 0.5f * (phi + omega), pm = 0.5f * (phi - omega);
        float epr = cosf(po), epi = -sinf(po);
        float emr = cosf(pm), emi = -sinf(pm);
        float* u = umat_s + tid * 8;
        u[0] = epr * c;  u[1] = epi * c;     // u00
        u[2] = -emr * s; u[3] = emi * s;     // u01 = -conj(em)*s
        u[4] = emr * s;  u[5] = emi * s;     // u10
        u[6] = epr * c;  u[7] = -epi * c;    // u11 = conj(ep)*c
    }

    // ---- phase 1: enc, 8-way split-K (proven form: 64 scalar floats live) --
    int lane = tid & 63;
    int wave = tid >> 6;                    // 0..7
    int swave = __builtin_amdgcn_readfirstlane(wave);
    size_t row = (size_t)blockIdx.x * 64 + lane;
    const float2* x2 = (const float2*)(x + row * 512 + swave * 64);
    const float* wseg = w1 + swave * 64 * 32;  // wave-uniform -> scalar loads

    float acc[32];
#pragma unroll
    for (int j = 0; j < 32; ++j) acc[j] = 0.f;

#pragma clang loop unroll(disable)
    for (int k2 = 0; k2 < 32; ++k2) {
        float2 xv = x2[k2];
        const float* wr = wseg + k2 * 64;
#pragma unroll
        for (int j = 0; j < 32; ++j) acc[j] = fmaf(wr[j], xv.x, acc[j]);
#pragma unroll
        for (int j = 0; j < 32; ++j) acc[j] = fmaf(wr[32 + j], xv.y, acc[j]);
    }
#pragma unroll
    for (int j = 0; j < 32; ++j) part[wave][lane][j] = acc[j];
    __syncthreads();

    // reduce 8 partials + bias + tanh -> hsh (aliases part[0]; each (rl,j)
    // slot owned by exactly one thread)
    {
        int rl = tid & 63;
        int jg = (tid >> 6) * 4;
#pragma unroll
        for (int jj = 0; jj < 4; ++jj) {
            int j = jg + jj;
            float v = b1[j];
#pragma unroll
            for (int w = 0; w < 8; ++w) v += part[w][rl][j];
            hsh[rl][j] = tanhf(v);
        }
    }
    __syncthreads();

    // ---- phase 2: angles -> cos/sin (384 threads: 64 rows x 6 q) -----------
    if (tid < 384) {
        int row_a = tid & 63;
        int q = tid >> 6;   // 0..5
        float a = b2[q];
#pragma unroll
        for (int j = 0; j < 32; ++j) a = fmaf(hsh[row_a][j], w2[j * 6 + q], a);
        a *= 0.5f;
        casa[row_a][q * 2]     = cosf(a);
        casa[row_a][q * 2 + 1] = sinf(a);
    }
    __syncthreads();

    // ---- phase 3: circuit, 8 threads per sample ----------------------------
    int s8 = lane & 7;
    int p = lane >> 3;                  // 0..7
    int samp = wave * 8 + s8;           // 0..63
    bool pb4 = (p & 4) != 0, pb2 = (p & 2) != 0, pb1 = (p & 1) != 0;

    float ca[6], sa[6];
#pragma unroll
    for (int q = 0; q < 6; ++q) { ca[q] = casa[samp][q * 2]; sa[q] = casa[samp][q * 2 + 1]; }

    float fr[8], fi[8];
#pragma unroll
    for (int j = 0; j < 8; ++j) { fr[j] = 0.f; fi[j] = 0.f; }
    fr[0] = (p == 0) ? 1.f : 0.f;

#pragma clang loop unroll(disable)
    for (int layer = 0; layer < 3; ++layer) {
        const float* ub = umat_s + layer * 48;
#define MAT(Q)                                                            \
        const float* u = ub + (Q) * 8;                                    \
        float c = ca[Q], ss = sa[Q];                                      \
        float m00r = u[0] * c + u[2] * ss, m00i = u[1] * c + u[3] * ss;   \
        float m01r = u[2] * c - u[0] * ss, m01i = u[3] * c - u[1] * ss;   \
        float m10r = u[4] * c + u[6] * ss, m10i = u[5] * c + u[7] * ss;   \
        float m11r = u[6] * c - u[4] * ss, m11i = u[7] * c - u[5] * ss;
        { MAT(0) apply_cross<32>(fr, fi, pb4, m00r, m00i, m01r, m01i, m10r, m10i, m11r, m11i); }
        { MAT(1) apply_cross<16>(fr, fi, pb2, m00r, m00i, m01r, m01i, m10r, m10i, m11r, m11i); }
        { MAT(2) apply_cross<8>(fr, fi, pb1, m00r, m00i, m01r, m01i, m10r, m10i, m11r, m11i); }
        { MAT(3) apply_local<4>(fr, fi, m00r, m00i, m01r, m01i, m10r, m10i, m11r, m11i); }
        { MAT(4) apply_local<2>(fr, fi, m00r, m00i, m01r, m01i, m10r, m10i, m11r, m11i); }
        { MAT(5) apply_local<1>(fr, fi, m00r, m00i, m01r, m01i, m10r, m10i, m11r, m11i); }
#undef MAT
        // CNOT(0,1): control bit32 (p&4) -> flip bit16: exchange lane^16
#pragma unroll
        for (int j = 0; j < 8; ++j) {
            float pr = __shfl_xor(fr[j], 16);
            float pi = __shfl_xor(fi[j], 16);
            fr[j] = pb4 ? pr : fr[j];
            fi[j] = pb4 ? pi : fi[j];
        }
        // CNOT(2,3): control bit8 (p&1) -> flip bit4 (local j^4)
        {
            float tr[8], ti[8];
#pragma unroll
            for (int j = 0; j < 8; ++j) { tr[j] = fr[j]; ti[j] = fi[j]; }
#pragma unroll
            for (int j = 0; j < 8; ++j) {
                fr[j] = pb1 ? tr[j ^ 4] : tr[j];
                fi[j] = pb1 ? ti[j ^ 4] : ti[j];
            }
        }
        // CNOT(4,5): control bit2 (j&2) -> flip bit1
        SWAP2(2, 3) SWAP2(6, 7)
        // CNOT(1,2): control bit16 (p&2) -> flip bit8: exchange lane^8
#pragma unroll
        for (int j = 0; j < 8; ++j) {
            float pr = __shfl_xor(fr[j], 8);
            float pi = __shfl_xor(fi[j], 8);
            fr[j] = pb2 ? pr : fr[j];
            fi[j] = pb2 ? pi : fi[j];
        }
        // CNOT(3,4): control bit4 (j&4) -> flip bit2
        SWAP2(4, 6) SWAP2(5, 7)
        // CNOT(5,0): control bit1 (j odd) -> flip bit32: exchange lane^32
#pragma unroll
        for (int j = 1; j < 8; j += 2) {
            fr[j] = __shfl_xor(fr[j], 32);
            fi[j] = __shfl_xor(fi[j], 32);
        }
    }

    // ---- z expectations: per-thread partials, butterfly over 8 parts -------
    float zt = 0.f, z3 = 0.f, z4 = 0.f, z5 = 0.f;
#pragma unroll
    for (int j = 0; j < 8; ++j) {
        float pp = fr[j] * fr[j] + fi[j] * fi[j];
        zt += pp;
        z3 += (j & 4) ? -pp : pp;
        z4 += (j & 2) ? -pp : pp;
        z5 += (j & 1) ? -pp : pp;
    }
    float zz[6];
    zz[0] = pb4 ? -zt : zt;
    zz[1] = pb2 ? -zt : zt;
    zz[2] = pb1 ? -zt : zt;
    zz[3] = z3; zz[4] = z4; zz[5] = z5;
#pragma unroll
    for (int q = 0; q < 6; ++q) {
        zz[q] += __shfl_xor(zz[q], 8);
        zz[q] += __shfl_xor(zz[q], 16);
        zz[q] += __shfl_xor(zz[q], 32);
    }

    // ---- phase 4: head layer 1 -> g in LDS (bf16, XOR-swizzled) ------------
    // Thread (samp, p) owns cols [p*16, p*16+16): same formula/order as the
    // proven kernel -> identical bits. Swizzle: 16-B unit u -> u ^ (row&7)
    // (G4 recipe) so GEMM-phase ds_read_b128 across rows is conflict-light.
    {
        int a7 = samp & 7;
#pragma unroll
        for (int half = 0; half < 2; ++half) {
            ushort8 pk;
#pragma unroll
            for (int jj = 0; jj < 8; ++jj) {
                int j = p * 16 + half * 8 + jj;
                float a = hb1[j];
#pragma unroll
                for (int q = 0; q < 6; ++q) a = fmaf(zz[q], hw1[q * 128 + j], a);
                a = fmaxf(a, 0.f);
                pk[jj] = f2bf(a);
            }
            int u = (p * 2 + half) ^ a7;
            *(ushort8*)(gl + samp * 256 + u * 16) = pk;
        }
    }
    __syncthreads();

    // ---- phase 5: head GEMM — out[64 rows][1296] = g_lds @ w2t^T + b2 ------
    // Same MFMA tiling/accumulation order and store indexing as the proven
    // head_gemm (bit-identical output). B-frags from LDS (swizzled read).
    {
        int l15 = lane & 15, quad = lane >> 4;
        int row0 = blockIdx.x * 64;
        int a7 = l15 & 7;                 // (sub*16 + l15) & 7 == l15 & 7

        for (int n = wave; n < 27; n += 8) {
            int col0 = n * 48;
            const unsigned short* ap = w2t + (size_t)(col0 + l15) * 128 + quad * 8;

            floatx4 acc[12];  // [t][sub]
#pragma unroll
            for (int i = 0; i < 12; ++i) acc[i] = (floatx4)0.f;

#pragma unroll
            for (int ks = 0; ks < 4; ++ks) {
                bf16x8 af[3], bf[4];
#pragma unroll
                for (int t = 0; t < 3; ++t)
                    af[t] = *(const bf16x8*)(ap + (size_t)t * 16 * 128 + ks * 32);
#pragma unroll
                for (int sub = 0; sub < 4; ++sub) {
                    int rowg = sub * 16 + l15;
                    int u = (quad + 4 * ks) ^ a7;
                    bf[sub] = *(const bf16x8*)(gl + rowg * 256 + u * 16);
                }
#pragma unroll
                for (int t = 0; t < 3; ++t)
#pragma unroll
                    for (int sub = 0; sub < 4; ++sub)
                        acc[t * 4 + sub] = __builtin_amdgcn_mfma_f32_16x16x32_bf16(
                            af[t], bf[sub], acc[t * 4 + sub], 0, 0, 0);
            }

#pragma unroll
            for (int t = 0; t < 3; ++t) {
                const float* bb = hb2 + col0 + t * 16 + quad * 4;
                floatx4 bias = { bb[0], bb[1], bb[2], bb[3] };
#pragma unroll
                for (int sub = 0; sub < 4; ++sub) {
                    floatx4 v = acc[t * 4 + sub] + bias;
                    floatx4* dst = (floatx4*)(out +
                        (size_t)(row0 + sub * 16 + l15) * 1296 + col0 + t * 16 + quad * 4);
                    *dst = v;   // plain store: L2 merges seams within the block's rows
                }
            }
        }
    }
}

// ---------------------------------------------------------------------------
extern "C" void kernel_launch(void* const* d_in, const int* in_sizes, int n_in,
                              void* d_out, int out_size, void* d_ws, size_t ws_size,
                              hipStream_t stream) {
    const float* x   = (const float*)d_in[0];
    const float* ew1 = (const float*)d_in[1];
    const float* eb1 = (const float*)d_in[2];
    const float* ew2 = (const float*)d_in[3];
    const float* eb2 = (const float*)d_in[4];
    const float* qw  = (const float*)d_in[5];
    const float* hw1 = (const float*)d_in[6];
    const float* hb1 = (const float*)d_in[7];
    const float* hw2 = (const float*)d_in[8];
    const float* hb2 = (const float*)d_in[9];
    float* out = (float*)d_out;

    char* ws = (char*)d_ws;
    unsigned short* w2t = (unsigned short*)(ws);   // 1296*128*2 = 331776 B

    prep_kernel<<<dim3(41), dim3(512), 0, stream>>>(hw2, w2t);
    mega_kernel<<<dim3(512), dim3(512), 0, stream>>>(
        x, ew1, eb1, ew2, eb2, qw, hw1, hb1, w2t, hb2, out);
}